// Round 2
// baseline (632.443 us; speedup 1.0000x reference)
//
#include <hip/hip_runtime.h>
#include <hip/hip_cooperative_groups.h>
#include <math.h>

namespace cg = cooperative_groups;

#define NB 32
#define NN 512
#define DD 256

constexpr float INV_EPS   = 10.0f;
constexpr float F_TINY    = 1e-16f;
constexpr float F_NORMEPS = 1e-8f;
constexpr float MARG      = 1.0f / 512.0f;   // a = b = 1/n

// ---------------------------------------------------------------------------
// row norms of x and y: one wave per row (256 floats -> float4 per lane)
// also zeroes cost[0..31] (d_out is re-poisoned before every launch)
// ---------------------------------------------------------------------------
__global__ void norms_k(const float* __restrict__ x, const float* __restrict__ y,
                        float* __restrict__ nx, float* __restrict__ ny,
                        float* __restrict__ cost) {
    if (blockIdx.x == 0 && threadIdx.x < NB) cost[threadIdx.x] = 0.0f;
    int w = threadIdx.x >> 6, lane = threadIdx.x & 63;
    int row = blockIdx.x * 4 + w;             // 0 .. 2*NB*NN-1  (8192 blocks)
    const float* base = (row < NB * NN) ? (x + (size_t)row * DD)
                                        : (y + (size_t)(row - NB * NN) * DD);
    float4 v4 = ((const float4*)base)[lane];
    float ss = v4.x * v4.x + v4.y * v4.y + v4.z * v4.z + v4.w * v4.w;
#pragma unroll
    for (int off = 32; off; off >>= 1) ss += __shfl_xor(ss, off);
    if (lane == 0) {
        float nv = sqrtf(ss);
        if (row < NB * NN) nx[row] = nv; else ny[row - NB * NN] = nv;
    }
}

// ---------------------------------------------------------------------------
// C[b,n,m] = 1 - <x_n,y_m>/max(|x_n||y_m|, 1e-8)
// 128x128 tile, BK=16, 256 threads, 8x8 micro-tile. fp32 vector FMA.
// ---------------------------------------------------------------------------
__global__ __launch_bounds__(256) void gemm_cos(
        const float* __restrict__ x, const float* __restrict__ y,
        const float* __restrict__ nx, const float* __restrict__ ny,
        float* __restrict__ C) {
    int blk = blockIdx.x;
    int b  = blk >> 4;
    int ti = (blk >> 2) & 3, tj = blk & 3;
    __shared__ float As[16][128];   // [k][row]
    __shared__ float Bs[16][128];   // [k][col]
    const float* xb = x + ((size_t)b * NN + ti * 128) * DD;
    const float* yb = y + ((size_t)b * NN + tj * 128) * DD;
    int tid = threadIdx.x;
    int ty = tid >> 4, tx = tid & 15;

    float acc[8][8];
#pragma unroll
    for (int i = 0; i < 8; ++i)
#pragma unroll
        for (int j = 0; j < 8; ++j) acc[i][j] = 0.0f;

    for (int k0 = 0; k0 < DD; k0 += 16) {
#pragma unroll
        for (int s = 0; s < 2; ++s) {
            int f = s * 256 + tid;          // 0..511
            int row = f >> 2;               // 0..127
            int kq  = (f & 3) << 2;         // 0,4,8,12
            float4 va = *(const float4*)(xb + (size_t)row * DD + k0 + kq);
            As[kq + 0][row] = va.x; As[kq + 1][row] = va.y;
            As[kq + 2][row] = va.z; As[kq + 3][row] = va.w;
            float4 vb = *(const float4*)(yb + (size_t)row * DD + k0 + kq);
            Bs[kq + 0][row] = vb.x; Bs[kq + 1][row] = vb.y;
            Bs[kq + 2][row] = vb.z; Bs[kq + 3][row] = vb.w;
        }
        __syncthreads();
#pragma unroll
        for (int kk = 0; kk < 16; ++kk) {
            float a[8], bb[8];
            *(float4*)&a[0]  = *(const float4*)&As[kk][ty * 8];
            *(float4*)&a[4]  = *(const float4*)&As[kk][ty * 8 + 4];
            *(float4*)&bb[0] = *(const float4*)&Bs[kk][tx * 8];
            *(float4*)&bb[4] = *(const float4*)&Bs[kk][tx * 8 + 4];
#pragma unroll
            for (int i = 0; i < 8; ++i)
#pragma unroll
                for (int j = 0; j < 8; ++j)
                    acc[i][j] = fmaf(a[i], bb[j], acc[i][j]);
        }
        __syncthreads();
    }

    int r0 = ti * 128 + ty * 8, c0 = tj * 128 + tx * 8;
    float nxr[8], nyc[8];
#pragma unroll
    for (int i = 0; i < 8; ++i) {
        nxr[i] = nx[b * NN + r0 + i];
        nyc[i] = ny[b * NN + c0 + i];
    }
    float* Cb = C + (size_t)b * NN * NN;
#pragma unroll
    for (int i = 0; i < 8; ++i) {
        float o[8];
#pragma unroll
        for (int j = 0; j < 8; ++j)
            o[j] = 1.0f - acc[i][j] / fmaxf(nxr[i] * nyc[j], F_NORMEPS);
        float4 w0 = make_float4(o[0], o[1], o[2], o[3]);
        float4 w1 = make_float4(o[4], o[5], o[6], o[7]);
        *(float4*)(Cb + (size_t)(r0 + i) * NN + c0)     = w0;
        *(float4*)(Cb + (size_t)(r0 + i) * NN + c0 + 4) = w1;
    }
}

// ---------------------------------------------------------------------------
// All 15 Sinkhorn iterations in ONE cooperative kernel.
// E = exp(-C/eps) lives in registers (64 floats/thread).
// State: A_n = exp(alpha_n/eps), B_m = exp(beta_m/eps) (multiplicative).
//   u_n = a/(A_n * sum_m E*(B_m v_m) + tiny);  A_n *= u_n
//   v_m = b/(B_m * sum_n E*A_n + tiny);        B_m *= v_m   (A already absorbed)
// 256 blocks x 512 threads: 8 blocks/batch (same XCD via blk%8 swizzle),
// block owns 64 rows; wave owns 8 rows; lane owns cols {4l..4l+3, 256+4l..+3}.
// One grid.sync per iteration; colpart double-buffered (race-free).
// ---------------------------------------------------------------------------
__global__ __launch_bounds__(512, 2) void sink_all(
        const float* __restrict__ C, float* __restrict__ cp0,
        float* __restrict__ cp1, float* __restrict__ P, float* __restrict__ Q) {
    int blk = blockIdx.x;
    int xcd = blk & 7, qq = blk >> 3;
    int o = qq & 7;                       // block's slot within its batch
    int b = ((qq >> 3) << 3) | xcd;       // batch; all 8 slots share blk%8 (XCD)
    int blkbase = blk - 8 * o;            // slot-0 block id of this batch
    int t = threadIdx.x, w = t >> 6, l = t & 63;
    int r0 = o * 64 + w * 8;              // wave's first row within batch

    __shared__ float sW[NN];              // B_m * v_m  (u-phase weights)
    __shared__ float sBB[NN];             // B_m
    __shared__ float sWP[8][NN];          // per-wave column partials

    // ---- load E into registers: E[i][e], e<4 -> col 4l+e, e>=4 -> col 256+4l+e-4
    float E[8][8];
    const float* Cb = C + ((size_t)b * NN + r0) * NN;
#pragma unroll
    for (int i = 0; i < 8; ++i) {
        const float* row = Cb + (size_t)i * NN;
        float4 c0 = *(const float4*)(row + 4 * l);
        float4 c1 = *(const float4*)(row + 256 + 4 * l);
        E[i][0] = __expf(-INV_EPS * c0.x);
        E[i][1] = __expf(-INV_EPS * c0.y);
        E[i][2] = __expf(-INV_EPS * c0.z);
        E[i][3] = __expf(-INV_EPS * c0.w);
        E[i][4] = __expf(-INV_EPS * c1.x);
        E[i][5] = __expf(-INV_EPS * c1.y);
        E[i][6] = __expf(-INV_EPS * c1.z);
        E[i][7] = __expf(-INV_EPS * c1.w);
    }
    float A[8], ulast[8];
#pragma unroll
    for (int i = 0; i < 8; ++i) { A[i] = 1.0f; ulast[i] = 1.0f; }
    sW[t]  = 1.0f;    // B=1, v=1
    sBB[t] = 1.0f;
    __syncthreads();

    cg::grid_group grid = cg::this_grid();

#pragma unroll 1
    for (int it = 0; it < 15; ++it) {
        float* cp = (it & 1) ? cp1 : cp0;

        // ---- Phase A: u for own 8 rows (per wave)
        float wr[8];
        *(float4*)&wr[0] = *(const float4*)&sW[4 * l];
        *(float4*)&wr[4] = *(const float4*)&sW[256 + 4 * l];
#pragma unroll
        for (int i = 0; i < 8; ++i) {
            float s = 0.0f;
#pragma unroll
            for (int e = 0; e < 8; ++e) s = fmaf(E[i][e], wr[e], s);
#pragma unroll
            for (int off = 32; off; off >>= 1) s += __shfl_xor(s, off);
            float uu = MARG / (A[i] * s + F_TINY);
            A[i] *= uu;                  // A_new = A_old * u  (what v-phase needs)
            ulast[i] = uu;
        }

        // ---- Phase B: column partials over own 8 rows
        float p[8];
#pragma unroll
        for (int e = 0; e < 8; ++e) {
            float s = 0.0f;
#pragma unroll
            for (int i = 0; i < 8; ++i) s = fmaf(E[i][e], A[i], s);
            p[e] = s;
        }
        *(float4*)&sWP[w][4 * l]       = make_float4(p[0], p[1], p[2], p[3]);
        *(float4*)&sWP[w][256 + 4 * l] = make_float4(p[4], p[5], p[6], p[7]);
        __syncthreads();
        float cs = 0.0f;
#pragma unroll
        for (int ww = 0; ww < 8; ++ww) cs += sWP[ww][t];
        cp[(size_t)blk * NN + t] = cs;   // block's col partial, coalesced

        grid.sync();

        // ---- Phase C: every block redundantly finishes v for all 512 cols
        float sv = 0.0f;
#pragma unroll
        for (int k = 0; k < 8; ++k)
            sv += cp[(size_t)(blkbase + 8 * k) * NN + t];
        float Bc = sBB[t];
        float vv = MARG / (Bc * sv + F_TINY);
        Bc *= vv;                        // B_new = B_old * v
        sBB[t] = Bc;
        sW[t]  = Bc * vv;                // next u-phase weight = B_new * v
        __syncthreads();
    }

    // ---- final factors for pi: P_n = A_final*u_final, Q_m = B_final*v_final (=sW)
    if (l == 0) {
#pragma unroll
        for (int i = 0; i < 8; ++i)
            P[b * NN + r0 + i] = A[i] * ulast[i];
    }
    if (o == 0) Q[b * NN + t] = sW[t];
}

// ---------------------------------------------------------------------------
// pi = P_n * Q_m * exp(-C/eps);  cost_b = sum pi*C
// grid 512 x 256: block handles 32 rows of one batch
// ---------------------------------------------------------------------------
__global__ __launch_bounds__(256) void pi_cost(
        const float* __restrict__ C, const float* __restrict__ P,
        const float* __restrict__ Q, float* __restrict__ pi,
        float* __restrict__ cost) {
    int b = blockIdx.x >> 4, rg = blockIdx.x & 15;
    __shared__ float sQ[NN];
    __shared__ float sPart[4];
    for (int i = threadIdx.x; i < NN; i += 256) sQ[i] = Q[b * NN + i];
    __syncthreads();
    int w = threadIdx.x >> 6, l = threadIdx.x & 63;
    float q0[8];
    *(float4*)&q0[0] = *(const float4*)&sQ[4 * l];
    *(float4*)&q0[4] = *(const float4*)&sQ[256 + 4 * l];
    const float* Cb = C + (size_t)b * NN * NN;
    float* pib = pi + (size_t)b * NN * NN;
    float csum = 0.0f;
#pragma unroll 1
    for (int i = 0; i < 8; ++i) {
        int r = rg * 32 + w * 8 + i;
        float pf = P[b * NN + r];
        const float* crow = Cb + (size_t)r * NN;
        float* prow = pib + (size_t)r * NN;
        float4 c0 = *(const float4*)(crow + 4 * l);
        float4 c1 = *(const float4*)(crow + 256 + 4 * l);
        float pv0 = pf * q0[0] * __expf(-INV_EPS * c0.x);
        float pv1 = pf * q0[1] * __expf(-INV_EPS * c0.y);
        float pv2 = pf * q0[2] * __expf(-INV_EPS * c0.z);
        float pv3 = pf * q0[3] * __expf(-INV_EPS * c0.w);
        float pv4 = pf * q0[4] * __expf(-INV_EPS * c1.x);
        float pv5 = pf * q0[5] * __expf(-INV_EPS * c1.y);
        float pv6 = pf * q0[6] * __expf(-INV_EPS * c1.z);
        float pv7 = pf * q0[7] * __expf(-INV_EPS * c1.w);
        *(float4*)(prow + 4 * l)       = make_float4(pv0, pv1, pv2, pv3);
        *(float4*)(prow + 256 + 4 * l) = make_float4(pv4, pv5, pv6, pv7);
        csum = fmaf(pv0, c0.x, csum); csum = fmaf(pv1, c0.y, csum);
        csum = fmaf(pv2, c0.z, csum); csum = fmaf(pv3, c0.w, csum);
        csum = fmaf(pv4, c1.x, csum); csum = fmaf(pv5, c1.y, csum);
        csum = fmaf(pv6, c1.z, csum); csum = fmaf(pv7, c1.w, csum);
    }
#pragma unroll
    for (int off = 32; off; off >>= 1) csum += __shfl_xor(csum, off);
    if (l == 0) sPart[w] = csum;
    __syncthreads();
    if (threadIdx.x == 0) {
        float tot = sPart[0] + sPart[1] + sPart[2] + sPart[3];
        atomicAdd(&cost[b], tot);
    }
}

// ---------------------------------------------------------------------------
extern "C" void kernel_launch(void* const* d_in, const int* in_sizes, int n_in,
                              void* d_out, int out_size, void* d_ws, size_t ws_size,
                              hipStream_t stream) {
    const float* x = (const float*)d_in[0];
    const float* y = (const float*)d_in[1];
    float* out  = (float*)d_out;
    float* cost = out;                                   // [32]
    float* pi   = out + 32;                              // [32*512*512]
    float* C    = out + 32 + (size_t)NB * NN * NN;       // [32*512*512]

    float* ws = (float*)d_ws;
    float* nx = ws;                   // 16384
    float* ny = ws + 16384;           // 16384
    float* P  = ws + 32768;           // 16384
    float* Q  = ws + 49152;           // 16384

    // colpart double-buffer lives in the pi region (pi is fully rewritten later)
    float* cp0 = pi;                  // 256*512 floats
    float* cp1 = pi + 256 * NN;       // 256*512 floats

    norms_k<<<dim3(8192), dim3(256), 0, stream>>>(x, y, nx, ny, cost);
    gemm_cos<<<dim3(512), dim3(256), 0, stream>>>(x, y, nx, ny, C);

    void* args[] = { (void*)&C, (void*)&cp0, (void*)&cp1, (void*)&P, (void*)&Q };
    hipLaunchCooperativeKernel((void*)sink_all, dim3(256), dim3(512),
                               args, 0, stream);

    pi_cost<<<dim3(512), dim3(256), 0, stream>>>(C, P, Q, pi, cost);
}

// Round 3
// 264.828 us; speedup vs baseline: 2.3881x; 2.3881x over previous
//
#include <hip/hip_runtime.h>
#include <math.h>

#define NB 32
#define NN 512
#define DD 256

constexpr float INV_EPS   = 10.0f;
constexpr float F_TINY    = 1e-16f;
constexpr float F_NORMEPS = 1e-8f;
constexpr float MARG      = 1.0f / 512.0f;   // a = b = 1/n

// ---------------------------------------------------------------------------
// row norms of x and y: one wave per row; also zeroes cost[0..31]
// ---------------------------------------------------------------------------
__global__ void norms_k(const float* __restrict__ x, const float* __restrict__ y,
                        float* __restrict__ nx, float* __restrict__ ny,
                        float* __restrict__ cost) {
    if (blockIdx.x == 0 && threadIdx.x < NB) cost[threadIdx.x] = 0.0f;
    int w = threadIdx.x >> 6, lane = threadIdx.x & 63;
    int row = blockIdx.x * 4 + w;             // 0 .. 2*NB*NN-1  (8192 blocks)
    const float* base = (row < NB * NN) ? (x + (size_t)row * DD)
                                        : (y + (size_t)(row - NB * NN) * DD);
    float4 v4 = ((const float4*)base)[lane];
    float ss = v4.x * v4.x + v4.y * v4.y + v4.z * v4.z + v4.w * v4.w;
#pragma unroll
    for (int off = 32; off; off >>= 1) ss += __shfl_xor(ss, off);
    if (lane == 0) {
        float nv = sqrtf(ss);
        if (row < NB * NN) nx[row] = nv; else ny[row - NB * NN] = nv;
    }
}

// ---------------------------------------------------------------------------
// C[b,n,m] = 1 - <x_n,y_m>/max(|x_n||y_m|, 1e-8)
// 128x128 tile, BK=16, 256 threads, 8x8 micro-tile. fp32 vector FMA.
// ---------------------------------------------------------------------------
__global__ __launch_bounds__(256) void gemm_cos(
        const float* __restrict__ x, const float* __restrict__ y,
        const float* __restrict__ nx, const float* __restrict__ ny,
        float* __restrict__ C) {
    int blk = blockIdx.x;
    int b  = blk >> 4;
    int ti = (blk >> 2) & 3, tj = blk & 3;
    __shared__ float As[16][128];   // [k][row]
    __shared__ float Bs[16][128];   // [k][col]
    const float* xb = x + ((size_t)b * NN + ti * 128) * DD;
    const float* yb = y + ((size_t)b * NN + tj * 128) * DD;
    int tid = threadIdx.x;
    int ty = tid >> 4, tx = tid & 15;

    float acc[8][8];
#pragma unroll
    for (int i = 0; i < 8; ++i)
#pragma unroll
        for (int j = 0; j < 8; ++j) acc[i][j] = 0.0f;

    for (int k0 = 0; k0 < DD; k0 += 16) {
#pragma unroll
        for (int s = 0; s < 2; ++s) {
            int f = s * 256 + tid;          // 0..511
            int row = f >> 2;               // 0..127
            int kq  = (f & 3) << 2;         // 0,4,8,12
            float4 va = *(const float4*)(xb + (size_t)row * DD + k0 + kq);
            As[kq + 0][row] = va.x; As[kq + 1][row] = va.y;
            As[kq + 2][row] = va.z; As[kq + 3][row] = va.w;
            float4 vb = *(const float4*)(yb + (size_t)row * DD + k0 + kq);
            Bs[kq + 0][row] = vb.x; Bs[kq + 1][row] = vb.y;
            Bs[kq + 2][row] = vb.z; Bs[kq + 3][row] = vb.w;
        }
        __syncthreads();
#pragma unroll
        for (int kk = 0; kk < 16; ++kk) {
            float a[8], bb[8];
            *(float4*)&a[0]  = *(const float4*)&As[kk][ty * 8];
            *(float4*)&a[4]  = *(const float4*)&As[kk][ty * 8 + 4];
            *(float4*)&bb[0] = *(const float4*)&Bs[kk][tx * 8];
            *(float4*)&bb[4] = *(const float4*)&Bs[kk][tx * 8 + 4];
#pragma unroll
            for (int i = 0; i < 8; ++i)
#pragma unroll
                for (int j = 0; j < 8; ++j)
                    acc[i][j] = fmaf(a[i], bb[j], acc[i][j]);
        }
        __syncthreads();
    }

    int r0 = ti * 128 + ty * 8, c0 = tj * 128 + tx * 8;
    float nxr[8], nyc[8];
#pragma unroll
    for (int i = 0; i < 8; ++i) {
        nxr[i] = nx[b * NN + r0 + i];
        nyc[i] = ny[b * NN + c0 + i];
    }
    float* Cb = C + (size_t)b * NN * NN;
#pragma unroll
    for (int i = 0; i < 8; ++i) {
        float o[8];
#pragma unroll
        for (int j = 0; j < 8; ++j)
            o[j] = 1.0f - acc[i][j] / fmaxf(nxr[i] * nyc[j], F_NORMEPS);
        float4 w0 = make_float4(o[0], o[1], o[2], o[3]);
        float4 w1 = make_float4(o[4], o[5], o[6], o[7]);
        *(float4*)(Cb + (size_t)(r0 + i) * NN + c0)     = w0;
        *(float4*)(Cb + (size_t)(r0 + i) * NN + c0 + 4) = w1;
    }
}

// ---------------------------------------------------------------------------
// One Sinkhorn iteration per launch (t = 1..15). Stream order between
// launches provides the device-wide barrier (NO grid.sync).
//
// Block = 64-row stripe of one batch (8 blocks/batch, XCD-swizzled).
//  step 1 (t>=2): finish v_{t-1}: read col partials cp_prev (8 stripes),
//                 v = MARG/(B_{t-2}*sv+tiny); B_{t-1}=B*v; w = B_{t-1}*v.
//                 (redundant per block; o==0 writes B_{t-1} to ping-pong buf)
//  step 2: u_t row-local: E=exp(-C/eps) in regs, rowsum = E.w, shuffle-reduce;
//          u = MARG/(A*rowsum+tiny); A_t = A*u (A in global, block-exclusive)
//  step 3: col partials of E.A_t for own stripe -> cp_cur[blk].
// t==15 writes P = A_15*u_15 instead of A.
// ---------------------------------------------------------------------------
__global__ __launch_bounds__(512) void sink_iter(
        const float* __restrict__ C, const float* __restrict__ cp_prev,
        float* __restrict__ cp_cur, float* __restrict__ A_g,
        const float* __restrict__ B_rd, float* __restrict__ B_wr,
        float* __restrict__ P, int t) {
    int blk = blockIdx.x;
    int xcd = blk & 7, qq = blk >> 3;
    int o = qq & 7;                       // stripe slot within batch
    int b = ((qq >> 3) << 3) | xcd;       // batch (8 stripes share blk%8/XCD)
    int blkbase = blk - 8 * o;            // slot-0 block id of this batch
    int tt = threadIdx.x, w = tt >> 6, l = tt & 63;
    int r0 = o * 64 + w * 8;              // wave's first row

    __shared__ float sW[NN];              // w_m = B_m * v_m
    __shared__ float sWP[8][NN];          // per-wave column partials

    // ---- step 1: finish v_{t-1} (t>=2); t==1 has v_0=1, B_0=1
    if (t == 1) {
        sW[tt] = 1.0f;
    } else {
        float sv = 0.0f;
#pragma unroll
        for (int k = 0; k < 8; ++k)
            sv += cp_prev[(size_t)(blkbase + 8 * k) * NN + tt];
        float Bc = (t == 2) ? 1.0f : B_rd[b * NN + tt];
        float vv = MARG / (Bc * sv + F_TINY);
        float Bn = Bc * vv;
        sW[tt] = Bn * vv;
        if (o == 0) B_wr[b * NN + tt] = Bn;
    }

    // ---- load E stripe into registers (lane owns cols {4l..4l+3, 256+4l..+3})
    float E[8][8];
    const float* Cb = C + ((size_t)b * NN + r0) * NN;
#pragma unroll
    for (int i = 0; i < 8; ++i) {
        const float* row = Cb + (size_t)i * NN;
        float4 c0 = *(const float4*)(row + 4 * l);
        float4 c1 = *(const float4*)(row + 256 + 4 * l);
        E[i][0] = __expf(-INV_EPS * c0.x);
        E[i][1] = __expf(-INV_EPS * c0.y);
        E[i][2] = __expf(-INV_EPS * c0.z);
        E[i][3] = __expf(-INV_EPS * c0.w);
        E[i][4] = __expf(-INV_EPS * c1.x);
        E[i][5] = __expf(-INV_EPS * c1.y);
        E[i][6] = __expf(-INV_EPS * c1.z);
        E[i][7] = __expf(-INV_EPS * c1.w);
    }
    float A[8];
#pragma unroll
    for (int i = 0; i < 8; ++i)
        A[i] = (t == 1) ? 1.0f : A_g[b * NN + r0 + i];   // broadcast load
    __syncthreads();

    // ---- step 2: u for own 8 rows
    float wr[8];
    *(float4*)&wr[0] = *(const float4*)&sW[4 * l];
    *(float4*)&wr[4] = *(const float4*)&sW[256 + 4 * l];
#pragma unroll
    for (int i = 0; i < 8; ++i) {
        float s = 0.0f;
#pragma unroll
        for (int e = 0; e < 8; ++e) s = fmaf(E[i][e], wr[e], s);
#pragma unroll
        for (int off = 32; off; off >>= 1) s += __shfl_xor(s, off);
        float uu = MARG / (A[i] * s + F_TINY);
        A[i] *= uu;
        if (l == 0) {
            if (t == 15) P[b * NN + r0 + i] = A[i] * uu;  // A_15 * u_15
            else         A_g[b * NN + r0 + i] = A[i];
        }
    }

    // ---- step 3: column partials over own stripe with A_t
    float p[8];
#pragma unroll
    for (int e = 0; e < 8; ++e) {
        float s = 0.0f;
#pragma unroll
        for (int i = 0; i < 8; ++i) s = fmaf(E[i][e], A[i], s);
        p[e] = s;
    }
    *(float4*)&sWP[w][4 * l]       = make_float4(p[0], p[1], p[2], p[3]);
    *(float4*)&sWP[w][256 + 4 * l] = make_float4(p[4], p[5], p[6], p[7]);
    __syncthreads();
    float cs = 0.0f;
#pragma unroll
    for (int ww = 0; ww < 8; ++ww) cs += sWP[ww][tt];
    cp_cur[(size_t)blk * NN + tt] = cs;
}

// ---------------------------------------------------------------------------
// finish v_15 -> Q_m = B_15*v_15 (one block per batch; avoids cp/pi race)
// ---------------------------------------------------------------------------
__global__ __launch_bounds__(512) void finish_q(
        const float* __restrict__ cp, const float* __restrict__ B_rd,
        float* __restrict__ Q) {
    int b = blockIdx.x, tt = threadIdx.x;
    int blkbase = ((b >> 3) << 6) | (b & 7);
    float sv = 0.0f;
#pragma unroll
    for (int k = 0; k < 8; ++k)
        sv += cp[(size_t)(blkbase + 8 * k) * NN + tt];
    float Bc = B_rd[b * NN + tt];
    float vv = MARG / (Bc * sv + F_TINY);
    Q[b * NN + tt] = Bc * vv * vv;     // B_15 * v_15
}

// ---------------------------------------------------------------------------
// pi = P_n * Q_m * exp(-C/eps);  cost_b = sum pi*C
// ---------------------------------------------------------------------------
__global__ __launch_bounds__(256) void pi_cost(
        const float* __restrict__ C, const float* __restrict__ P,
        const float* __restrict__ Q, float* __restrict__ pi,
        float* __restrict__ cost) {
    int b = blockIdx.x >> 4, rg = blockIdx.x & 15;
    __shared__ float sQ[NN];
    __shared__ float sPart[4];
    for (int i = threadIdx.x; i < NN; i += 256) sQ[i] = Q[b * NN + i];
    __syncthreads();
    int w = threadIdx.x >> 6, l = threadIdx.x & 63;
    float q0[8];
    *(float4*)&q0[0] = *(const float4*)&sQ[4 * l];
    *(float4*)&q0[4] = *(const float4*)&sQ[256 + 4 * l];
    const float* Cb = C + (size_t)b * NN * NN;
    float* pib = pi + (size_t)b * NN * NN;
    float csum = 0.0f;
#pragma unroll 1
    for (int i = 0; i < 8; ++i) {
        int r = rg * 32 + w * 8 + i;
        float pf = P[b * NN + r];
        const float* crow = Cb + (size_t)r * NN;
        float* prow = pib + (size_t)r * NN;
        float4 c0 = *(const float4*)(crow + 4 * l);
        float4 c1 = *(const float4*)(crow + 256 + 4 * l);
        float pv0 = pf * q0[0] * __expf(-INV_EPS * c0.x);
        float pv1 = pf * q0[1] * __expf(-INV_EPS * c0.y);
        float pv2 = pf * q0[2] * __expf(-INV_EPS * c0.z);
        float pv3 = pf * q0[3] * __expf(-INV_EPS * c0.w);
        float pv4 = pf * q0[4] * __expf(-INV_EPS * c1.x);
        float pv5 = pf * q0[5] * __expf(-INV_EPS * c1.y);
        float pv6 = pf * q0[6] * __expf(-INV_EPS * c1.z);
        float pv7 = pf * q0[7] * __expf(-INV_EPS * c1.w);
        *(float4*)(prow + 4 * l)       = make_float4(pv0, pv1, pv2, pv3);
        *(float4*)(prow + 256 + 4 * l) = make_float4(pv4, pv5, pv6, pv7);
        csum = fmaf(pv0, c0.x, csum); csum = fmaf(pv1, c0.y, csum);
        csum = fmaf(pv2, c0.z, csum); csum = fmaf(pv3, c0.w, csum);
        csum = fmaf(pv4, c1.x, csum); csum = fmaf(pv5, c1.y, csum);
        csum = fmaf(pv6, c1.z, csum); csum = fmaf(pv7, c1.w, csum);
    }
#pragma unroll
    for (int off = 32; off; off >>= 1) csum += __shfl_xor(csum, off);
    if (l == 0) sPart[w] = csum;
    __syncthreads();
    if (threadIdx.x == 0) {
        float tot = sPart[0] + sPart[1] + sPart[2] + sPart[3];
        atomicAdd(&cost[b], tot);
    }
}

// ---------------------------------------------------------------------------
extern "C" void kernel_launch(void* const* d_in, const int* in_sizes, int n_in,
                              void* d_out, int out_size, void* d_ws, size_t ws_size,
                              hipStream_t stream) {
    const float* x = (const float*)d_in[0];
    const float* y = (const float*)d_in[1];
    float* out  = (float*)d_out;
    float* cost = out;                                   // [32]
    float* pi   = out + 32;                              // [32*512*512]
    float* C    = out + 32 + (size_t)NB * NN * NN;       // [32*512*512]

    float* ws = (float*)d_ws;
    float* nx = ws;                    // 16384
    float* ny = ws + 16384;            // 16384
    float* P  = ws + 32768;            // 16384
    float* Q  = ws + 49152;            // 16384
    float* A  = ws + 65536;            // 16384
    float* Bb[2] = { ws + 81920, ws + 98304 };   // ping-pong B (16384 each)

    // col-partial double-buffer in the pi region (pi rewritten at the end,
    // strictly after finish_q has consumed cp)
    float* cp[2] = { pi, pi + 256 * NN };

    norms_k<<<dim3(8192), dim3(256), 0, stream>>>(x, y, nx, ny, cost);
    gemm_cos<<<dim3(512), dim3(256), 0, stream>>>(x, y, nx, ny, C);

    for (int t = 1; t <= 15; ++t) {
        // launch t: reads B_{t-2} from Bb[t&1], writes B_{t-1} to Bb[(t-1)&1]
        sink_iter<<<dim3(256), dim3(512), 0, stream>>>(
            C, cp[(t - 1) & 1], cp[t & 1], A,
            Bb[t & 1], Bb[(t - 1) & 1], P, t);
    }
    // cp_15 is in cp[1]; B_14 is in Bb[0]
    finish_q<<<dim3(32), dim3(512), 0, stream>>>(cp[1], Bb[0], Q);
    pi_cost<<<dim3(512), dim3(256), 0, stream>>>(C, P, Q, pi, cost);
}